// Round 2
// baseline (279.970 us; speedup 1.0000x reference)
//
#include <hip/hip_runtime.h>

#define S_LEN 2048
#define BATCH 4
#define NH 8
#define DK 16
#define DM 256
#define DP 128  // NH*DK
#define SW (S_LEN / 64)  // packed mask words per row

__device__ __forceinline__ float dot4(float4 a, float4 b, float acc) {
    acc = fmaf(a.x, b.x, acc);
    acc = fmaf(a.y, b.y, acc);
    acc = fmaf(a.z, b.z, acc);
    acc = fmaf(a.w, b.w, acc);
    return acc;
}

// ---------------- Mask dtype detection + bit-packing ----------------
// flag==0 -> mask is int32 (0/1); flag!=0 -> mask is 1-byte bool
__global__ __launch_bounds__(256) void detect_mask_dtype(
    const unsigned int* __restrict__ m, int* __restrict__ flag)
{
    unsigned int u = m[blockIdx.x * 256 + threadIdx.x];  // first 1 MB only
    if (u & 0xFFFFFF00u) atomicOr(flag, 1);
}

__global__ __launch_bounds__(256) void pack_mask(
    const void* __restrict__ mraw, unsigned long long* __restrict__ packed,
    const int* __restrict__ flag)
{
    const size_t i = (size_t)blockIdx.x * 256 + threadIdx.x;
    int v;
    if (*flag == 0) v = ((const int*)mraw)[i] != 0;
    else            v = ((const unsigned char*)mraw)[i] != 0;
    unsigned long long b = __ballot(v);
    if ((threadIdx.x & 63) == 0) packed[i >> 6] = b;
}

// ---------------- Kernel 1: fused QKV projections ----------------
// X:[B*S,256] @ W:[256,128] -> [B,H,S,16] (per-head contiguous for attention)
__global__ __launch_bounds__(256) void proj_qkv(
    const float* __restrict__ Xq, const float* __restrict__ Xk, const float* __restrict__ Xv,
    const float* __restrict__ Wq, const float* __restrict__ Wk, const float* __restrict__ Wv,
    float* __restrict__ Qp, float* __restrict__ Kp, float* __restrict__ Vp)
{
    __shared__ float xs[3][8][DM];
    const int t = threadIdx.x;
    const int row0 = blockIdx.x * 8;

    // stage 8 rows of each of the 3 inputs: 6144 floats, 6 float4 per thread
    #pragma unroll
    for (int i = 0; i < 6; ++i) {
        int idx = (i * 256 + t) * 4;      // 0..6140
        int m = idx >> 11;                // which input
        int rem = idx & 2047;
        int r = rem >> 8;
        int k = rem & 255;
        const float* src = (m == 0) ? Xq : (m == 1) ? Xk : Xv;
        *(float4*)&xs[m][r][k] = *(const float4*)(src + (size_t)(row0 + r) * DM + k);
    }
    __syncthreads();

    const int c = t & 127;   // output column 0..127
    const int rh = t >> 7;   // row half: rows rh*4 .. rh*4+3
    float aq[4] = {0,0,0,0}, ak[4] = {0,0,0,0}, av[4] = {0,0,0,0};

    for (int k = 0; k < DM; k += 4) {
        const float wq0 = Wq[(k+0)*DP + c], wq1 = Wq[(k+1)*DP + c], wq2 = Wq[(k+2)*DP + c], wq3 = Wq[(k+3)*DP + c];
        const float wk0 = Wk[(k+0)*DP + c], wk1 = Wk[(k+1)*DP + c], wk2 = Wk[(k+2)*DP + c], wk3 = Wk[(k+3)*DP + c];
        const float wv0 = Wv[(k+0)*DP + c], wv1 = Wv[(k+1)*DP + c], wv2 = Wv[(k+2)*DP + c], wv3 = Wv[(k+3)*DP + c];
        #pragma unroll
        for (int r = 0; r < 4; ++r) {
            float4 x = *(const float4*)&xs[0][rh*4 + r][k];
            aq[r] = fmaf(x.x, wq0, fmaf(x.y, wq1, fmaf(x.z, wq2, fmaf(x.w, wq3, aq[r]))));
            float4 y = *(const float4*)&xs[1][rh*4 + r][k];
            ak[r] = fmaf(y.x, wk0, fmaf(y.y, wk1, fmaf(y.z, wk2, fmaf(y.w, wk3, ak[r]))));
            float4 z = *(const float4*)&xs[2][rh*4 + r][k];
            av[r] = fmaf(z.x, wv0, fmaf(z.y, wv1, fmaf(z.z, wv2, fmaf(z.w, wv3, av[r]))));
        }
    }

    const int h = c >> 4, d = c & 15;
    #pragma unroll
    for (int r = 0; r < 4; ++r) {
        int row = row0 + rh*4 + r;
        int b = row >> 11, s = row & (S_LEN - 1);
        size_t o = (((size_t)(b * NH + h)) * S_LEN + s) * DK + d;
        Qp[o] = aq[r];
        Kp[o] = ak[r];
        Vp[o] = av[r];
    }
}

// ---------------- Kernel 2: flash attention (fp32) ----------------
// grid (S/64, B*H); block 256 = 64 q-rows x 4 sub-threads
__global__ __launch_bounds__(256) void attn_fwd(
    const float* __restrict__ Qp, const float* __restrict__ Kp, const float* __restrict__ Vp,
    const unsigned long long* __restrict__ mpacked, float* __restrict__ ctx_out)
{
    const int bh = blockIdx.y;      // 0..31
    const int b = bh >> 3;
    const int h = bh & 7;
    const int q0 = blockIdx.x * 64;
    const int t = threadIdx.x;
    const int qi = t >> 2;          // q row within tile 0..63
    const int sub = t & 3;          // key sub-lane 0..3

    __shared__ __align__(16) float Kt[64][DK];
    __shared__ __align__(16) float Vt[64][DK];

    // Q row in registers, pre-scaled by 1/sqrt(dk)
    float4 q0v, q1v, q2v, q3v;
    {
        const float* qrow = Qp + (((size_t)bh * S_LEN) + q0 + qi) * DK;
        q0v = *(const float4*)(qrow + 0);
        q1v = *(const float4*)(qrow + 4);
        q2v = *(const float4*)(qrow + 8);
        q3v = *(const float4*)(qrow + 12);
        const float sc = 0.25f;
        q0v.x *= sc; q0v.y *= sc; q0v.z *= sc; q0v.w *= sc;
        q1v.x *= sc; q1v.y *= sc; q1v.z *= sc; q1v.w *= sc;
        q2v.x *= sc; q2v.y *= sc; q2v.z *= sc; q2v.w *= sc;
        q3v.x *= sc; q3v.y *= sc; q3v.z *= sc; q3v.w *= sc;
    }

    float m = -1e30f, l = 0.f;
    float ctx[16];
    #pragma unroll
    for (int d = 0; d < 16; ++d) ctx[d] = 0.f;

    const int kr = t >> 2;
    const int kd = (t & 3) * 4;
    const size_t kvbase = (size_t)bh * S_LEN * DK;
    const unsigned long long* mrowp = mpacked + ((size_t)b * S_LEN + q0 + qi) * SW;

    for (int k0 = 0; k0 < S_LEN; k0 += 64) {
        // stage K,V tile (64x16 f32 each), fully coalesced
        *(float4*)&Kt[kr][kd] = *(const float4*)(Kp + kvbase + (size_t)(k0 + kr) * DK + kd);
        *(float4*)&Vt[kr][kd] = *(const float4*)(Vp + kvbase + (size_t)(k0 + kr) * DK + kd);
        const unsigned long long mbits = mrowp[k0 >> 6];  // 64 mask bits for this q-row/tile
        __syncthreads();

        // 16 scores per thread: keys k = 4*i + sub
        float s[16];
        float lmax = -1e30f;
        #pragma unroll
        for (int i = 0; i < 16; ++i) {
            const int k = 4*i + sub;
            const float4 k0v = *(const float4*)&Kt[k][0];
            const float4 k1v = *(const float4*)&Kt[k][4];
            const float4 k2v = *(const float4*)&Kt[k][8];
            const float4 k3v = *(const float4*)&Kt[k][12];
            float acc = dot4(q0v, k0v, dot4(q1v, k1v, dot4(q2v, k2v, dot4(q3v, k3v, 0.f))));
            if ((mbits >> k) & 1ull) acc = -1e9f;   // mask==1 -> masked
            s[i] = acc;
            lmax = fmaxf(lmax, acc);
        }
        lmax = fmaxf(lmax, __shfl_xor(lmax, 1));
        lmax = fmaxf(lmax, __shfl_xor(lmax, 2));
        const float m_new = fmaxf(m, lmax);
        const float corr = __expf(m - m_new);
        l *= corr;
        #pragma unroll
        for (int d = 0; d < 16; ++d) ctx[d] *= corr;

        float p[16];
        float lsum = 0.f;
        #pragma unroll
        for (int i = 0; i < 16; ++i) { p[i] = __expf(s[i] - m_new); lsum += p[i]; }

        #pragma unroll
        for (int i = 0; i < 16; ++i) {
            const int k = 4*i + sub;
            const float pi = p[i];
            const float4 v0 = *(const float4*)&Vt[k][0];
            const float4 v1 = *(const float4*)&Vt[k][4];
            const float4 v2 = *(const float4*)&Vt[k][8];
            const float4 v3 = *(const float4*)&Vt[k][12];
            ctx[0]  = fmaf(pi, v0.x, ctx[0]);  ctx[1]  = fmaf(pi, v0.y, ctx[1]);
            ctx[2]  = fmaf(pi, v0.z, ctx[2]);  ctx[3]  = fmaf(pi, v0.w, ctx[3]);
            ctx[4]  = fmaf(pi, v1.x, ctx[4]);  ctx[5]  = fmaf(pi, v1.y, ctx[5]);
            ctx[6]  = fmaf(pi, v1.z, ctx[6]);  ctx[7]  = fmaf(pi, v1.w, ctx[7]);
            ctx[8]  = fmaf(pi, v2.x, ctx[8]);  ctx[9]  = fmaf(pi, v2.y, ctx[9]);
            ctx[10] = fmaf(pi, v2.z, ctx[10]); ctx[11] = fmaf(pi, v2.w, ctx[11]);
            ctx[12] = fmaf(pi, v3.x, ctx[12]); ctx[13] = fmaf(pi, v3.y, ctx[13]);
            ctx[14] = fmaf(pi, v3.z, ctx[14]); ctx[15] = fmaf(pi, v3.w, ctx[15]);
        }
        lsum += __shfl_xor(lsum, 1);
        lsum += __shfl_xor(lsum, 2);
        l += lsum;
        m = m_new;
        __syncthreads();
    }

    // combine the 4 sub-threads (m,l were quad-uniform every step)
    #pragma unroll
    for (int d = 0; d < 16; ++d) {
        ctx[d] += __shfl_xor(ctx[d], 1);
        ctx[d] += __shfl_xor(ctx[d], 2);
    }
    const float inv_l = 1.0f / l;
    float4 o;
    if (sub == 0)      o = make_float4(ctx[0],  ctx[1],  ctx[2],  ctx[3]);
    else if (sub == 1) o = make_float4(ctx[4],  ctx[5],  ctx[6],  ctx[7]);
    else if (sub == 2) o = make_float4(ctx[8],  ctx[9],  ctx[10], ctx[11]);
    else               o = make_float4(ctx[12], ctx[13], ctx[14], ctx[15]);
    o.x *= inv_l; o.y *= inv_l; o.z *= inv_l; o.w *= inv_l;
    // ctx_out layout [B, S, 128]
    *(float4*)(ctx_out + (((size_t)b * S_LEN) + q0 + qi) * DP + h * DK + sub * 4) = o;
}

// ---------------- Kernel 3: FC (ctx @ Wfc) + LayerNorm ----------------
// 4 rows per block; thread t owns output column t for all 4 rows
__global__ __launch_bounds__(256) void fc_ln(
    const float* __restrict__ ctx, const float* __restrict__ Wfc,
    const float* __restrict__ gamma, const float* __restrict__ beta,
    float* __restrict__ out)
{
    __shared__ float cs[4][DP];
    __shared__ float ys[4][256];
    __shared__ float red[8];
    const int t = threadIdx.x;
    const int row0 = blockIdx.x * 4;

    {
        int idx = t * 2;
        int r = idx >> 7, k = idx & 127;
        *(float2*)&cs[r][k] = *(const float2*)(ctx + (size_t)(row0 + r) * DP + k);
    }
    __syncthreads();

    float acc[4] = {0,0,0,0};
    for (int k = 0; k < DP; k += 4) {
        const float w0 = Wfc[(k+0)*DM + t];
        const float w1 = Wfc[(k+1)*DM + t];
        const float w2 = Wfc[(k+2)*DM + t];
        const float w3 = Wfc[(k+3)*DM + t];
        #pragma unroll
        for (int r = 0; r < 4; ++r) {
            float4 x = *(const float4*)&cs[r][k];
            acc[r] = fmaf(x.x, w0, fmaf(x.y, w1, fmaf(x.z, w2, fmaf(x.w, w3, acc[r]))));
        }
    }

    #pragma unroll
    for (int r = 0; r < 4; ++r) ys[r][t] = acc[r];
    __syncthreads();

    const int w = t >> 6, l = t & 63;
    {
        float a0 = ys[w][l], a1 = ys[w][l+64], a2 = ys[w][l+128], a3 = ys[w][l+192];
        float s1 = a0 + a1 + a2 + a3;
        float s2 = a0*a0 + a1*a1 + a2*a2 + a3*a3;
        #pragma unroll
        for (int off = 32; off; off >>= 1) {
            s1 += __shfl_xor(s1, off);
            s2 += __shfl_xor(s2, off);
        }
        if (l == 0) {
            float mu = s1 * (1.0f/256.0f);
            float var = s2 * (1.0f/256.0f) - mu*mu;
            red[w*2]     = mu;
            red[w*2 + 1] = rsqrtf(var + 1e-5f);
        }
    }
    __syncthreads();

    const float g = gamma[t], be = beta[t];
    #pragma unroll
    for (int r = 0; r < 4; ++r) {
        float y = (acc[r] - red[r*2]) * red[r*2 + 1];
        out[(size_t)(row0 + r) * DM + t] = fmaf(y, g, be);
    }
}

extern "C" void kernel_launch(void* const* d_in, const int* in_sizes, int n_in,
                              void* d_out, int out_size, void* d_ws, size_t ws_size,
                              hipStream_t stream)
{
    const float* Xq = (const float*)d_in[0];
    const float* Xk = (const float*)d_in[1];
    const float* Xv = (const float*)d_in[2];
    const void* mask_raw = d_in[3];       // int32 (expected) or 1-byte bool; detected on device
    const float* Wq  = (const float*)d_in[4];
    const float* Wk  = (const float*)d_in[5];
    const float* Wv  = (const float*)d_in[6];
    const float* Wfc = (const float*)d_in[7];
    const float* gamma = (const float*)d_in[8];
    const float* beta  = (const float*)d_in[9];
    float* out = (float*)d_out;

    const size_t headsz = (size_t)BATCH * NH * S_LEN * DK;      // 1M floats
    const size_t maskelems = (size_t)BATCH * S_LEN * S_LEN;     // 16.8M
    float* Qp  = (float*)d_ws;
    float* Kp  = Qp + headsz;
    float* Vp  = Kp + headsz;
    float* ctx = Vp + headsz;                                   // [B,S,128]
    unsigned long long* mpacked = (unsigned long long*)(ctx + (size_t)BATCH * S_LEN * DP);
    int* flag = (int*)(mpacked + maskelems / 64);

    hipMemsetAsync(flag, 0, sizeof(int), stream);
    detect_mask_dtype<<<dim3(1024), dim3(256), 0, stream>>>((const unsigned int*)mask_raw, flag);
    pack_mask<<<dim3(maskelems / 256), dim3(256), 0, stream>>>(mask_raw, mpacked, flag);

    proj_qkv<<<dim3(BATCH * S_LEN / 8), dim3(256), 0, stream>>>(Xq, Xk, Xv, Wq, Wk, Wv, Qp, Kp, Vp);
    attn_fwd<<<dim3(S_LEN / 64, BATCH * NH), dim3(256), 0, stream>>>(Qp, Kp, Vp, mpacked, ctx);
    fc_ln<<<dim3(BATCH * S_LEN / 4), dim3(256), 0, stream>>>(ctx, Wfc, gamma, beta, out);
}

// Round 3
// 165.813 us; speedup vs baseline: 1.6885x; 1.6885x over previous
//
#include <hip/hip_runtime.h>
#include <hip/hip_bf16.h>

#define S_LEN 2048
#define BATCH 4
#define NH 8
#define DK 16
#define DM 256
#define DP 128           // NH*DK
#define SW (S_LEN / 64)  // packed mask words per row
#define L2E 1.4426950408889634f

typedef short bf16x8 __attribute__((ext_vector_type(8)));
typedef short short4v __attribute__((ext_vector_type(4)));
typedef float f32x16 __attribute__((ext_vector_type(16)));

__device__ __forceinline__ short f2bf(float x) {
    __hip_bfloat16 h = __float2bfloat16(x);
    return __builtin_bit_cast(short, h);
}

// ---------------- Mask dtype detection + bit-packing ----------------
__global__ __launch_bounds__(256) void detect_mask_dtype(
    const unsigned int* __restrict__ m, int* __restrict__ flag)
{
    unsigned int u = m[blockIdx.x * 256 + threadIdx.x];  // first 1 MB only
    if (u & 0xFFFFFF00u) atomicOr(flag, 1);
}

__global__ __launch_bounds__(256) void pack_mask(
    const void* __restrict__ mraw, unsigned long long* __restrict__ packed,
    const int* __restrict__ flag)
{
    const size_t i = (size_t)blockIdx.x * 256 + threadIdx.x;
    int v;
    if (*flag == 0) v = ((const int*)mraw)[i] != 0;
    else            v = ((const unsigned char*)mraw)[i] != 0;
    unsigned long long b = __ballot(v);
    if ((threadIdx.x & 63) == 0) packed[i >> 6] = b;
}

// ---------------- Kernel 1: fused QKV projections (fp32 math, bf16 out) ----
// Q -> [B,H,S,16] bf16, pre-scaled by 0.25; K -> [B,H,S,16] bf16;
// V -> TRANSPOSED [B,H,16,S] bf16 (for the PV MFMA A-operand)
__global__ __launch_bounds__(256) void proj_qkv(
    const float* __restrict__ Xq, const float* __restrict__ Xk, const float* __restrict__ Xv,
    const float* __restrict__ Wq, const float* __restrict__ Wk, const float* __restrict__ Wv,
    short* __restrict__ Qb, short* __restrict__ Kb, short* __restrict__ Vb)
{
    __shared__ float xs[3][8][DM];
    const int t = threadIdx.x;
    const int row0 = blockIdx.x * 8;

    #pragma unroll
    for (int i = 0; i < 6; ++i) {
        int idx = (i * 256 + t) * 4;
        int m = idx >> 11;
        int rem = idx & 2047;
        int r = rem >> 8;
        int k = rem & 255;
        const float* src = (m == 0) ? Xq : (m == 1) ? Xk : Xv;
        *(float4*)&xs[m][r][k] = *(const float4*)(src + (size_t)(row0 + r) * DM + k);
    }
    __syncthreads();

    const int c = t & 127;
    const int rh = t >> 7;
    float aq[4] = {0,0,0,0}, ak[4] = {0,0,0,0}, av[4] = {0,0,0,0};

    for (int k = 0; k < DM; k += 4) {
        const float wq0 = Wq[(k+0)*DP + c], wq1 = Wq[(k+1)*DP + c], wq2 = Wq[(k+2)*DP + c], wq3 = Wq[(k+3)*DP + c];
        const float wk0 = Wk[(k+0)*DP + c], wk1 = Wk[(k+1)*DP + c], wk2 = Wk[(k+2)*DP + c], wk3 = Wk[(k+3)*DP + c];
        const float wv0 = Wv[(k+0)*DP + c], wv1 = Wv[(k+1)*DP + c], wv2 = Wv[(k+2)*DP + c], wv3 = Wv[(k+3)*DP + c];
        #pragma unroll
        for (int r = 0; r < 4; ++r) {
            float4 x = *(const float4*)&xs[0][rh*4 + r][k];
            aq[r] = fmaf(x.x, wq0, fmaf(x.y, wq1, fmaf(x.z, wq2, fmaf(x.w, wq3, aq[r]))));
            float4 y = *(const float4*)&xs[1][rh*4 + r][k];
            ak[r] = fmaf(y.x, wk0, fmaf(y.y, wk1, fmaf(y.z, wk2, fmaf(y.w, wk3, ak[r]))));
            float4 z = *(const float4*)&xs[2][rh*4 + r][k];
            av[r] = fmaf(z.x, wv0, fmaf(z.y, wv1, fmaf(z.z, wv2, fmaf(z.w, wv3, av[r]))));
        }
    }

    const int h = c >> 4, d = c & 15;
    const int row = row0 + rh*4;
    const int b = row >> 11, s = row & (S_LEN - 1);
    const size_t bh = (size_t)(b * NH + h);

    // Q,K: [bh][s][16] bf16, scalar stores (4 consecutive s rows)
    #pragma unroll
    for (int r = 0; r < 4; ++r) {
        size_t o = (bh * S_LEN + s + r) * DK + d;
        Qb[o] = f2bf(aq[r] * 0.25f);   // fold 1/sqrt(dk)
        Kb[o] = f2bf(ak[r]);
    }
    // V^T: [bh][d][s] bf16, one 8B store of 4 consecutive s
    short4v vv = { f2bf(av[0]), f2bf(av[1]), f2bf(av[2]), f2bf(av[3]) };
    *(short4v*)(Vb + (bh * DK + d) * S_LEN + s) = vv;
}

// ---------------- Kernel 2: MFMA flash attention ----------------
// grid (S/128, B*H); block 256 = 4 independent waves, each owns 32 q-rows.
// No LDS, no barriers: K/V stream through L1/L2 (128 KB per head).
// All-transposed dataflow:
//   S^T[k][q] = mfma_32x32x16(K_frag, Q^T_frag)   (lane owns q = lane&31)
//   ctx^T[d][q] += mfma_32x32x16(V^T_frag, P^T_frag) (P^T = D regs, no shuffle)
__global__ __launch_bounds__(256) void attn_mfma(
    const short* __restrict__ Qb, const short* __restrict__ Kb, const short* __restrict__ Vb,
    const unsigned long long* __restrict__ mp, float* __restrict__ ctx_out)
{
    const int bh = blockIdx.y;
    const int b = bh >> 3, h = bh & 7;
    const int wave = threadIdx.x >> 6, lane = threadIdx.x & 63;
    const int lq = lane & 31, hi = lane >> 5;
    const int qrow = blockIdx.x * 128 + wave * 32 + lq;

    // Q^T B-frag: lane needs Q[qrow][dk], dk = kb*8 + 4*hi + j
    union Frag { bf16x8 v; short4v h2[2]; };
    Frag qf;
    {
        const short* qp = Qb + ((size_t)bh * S_LEN + qrow) * DK;
        qf.h2[0] = *(const short4v*)(qp + 4*hi);
        qf.h2[1] = *(const short4v*)(qp + 8 + 4*hi);
    }

    f32x16 acc;
    #pragma unroll
    for (int i = 0; i < 16; ++i) acc[i] = 0.f;
    f32x16 zero = acc;

    float m = -1e30f, l = 0.f;

    const short* kbase = Kb + (size_t)bh * S_LEN * DK;
    const short* vrow  = Vb + ((size_t)bh * DK + (lq & 15)) * S_LEN;
    const unsigned long long* mrow = mp + ((size_t)b * S_LEN + qrow) * SW;

    for (int tile = 0; tile < S_LEN / 128; ++tile) {
        const int k0 = tile * 128;

        // ---- QK^T: 4 MFMAs -> 64 scores per lane (S^T: lane owns column q)
        f32x16 p[4];
        #pragma unroll
        for (int kt = 0; kt < 4; ++kt) {
            Frag kf;
            const short* kp = kbase + (size_t)(k0 + kt*32 + lq) * DK;
            kf.h2[0] = *(const short4v*)(kp + 4*hi);
            kf.h2[1] = *(const short4v*)(kp + 8 + 4*hi);
            p[kt] = __builtin_amdgcn_mfma_f32_32x32x16_bf16(kf.v, qf.v, zero, 0, 0, 0);
        }

        // ---- mask + tile max
        const unsigned long long W0 = mrow[tile*2]     >> (4*hi);
        const unsigned long long W1 = mrow[tile*2 + 1] >> (4*hi);
        float lmax = -1e30f;
        #pragma unroll
        for (int kt = 0; kt < 4; ++kt) {
            const unsigned long long W = (kt < 2) ? W0 : W1;
            #pragma unroll
            for (int r = 0; r < 16; ++r) {
                const int c = (kt & 1)*32 + (r & 3) + 8*(r >> 2);  // key idx minus 4*hi
                float sv = p[kt][r];
                sv = ((W >> c) & 1ull) ? -1e9f : sv;
                p[kt][r] = sv;
                lmax = fmaxf(lmax, sv);
            }
        }
        lmax = fmaxf(lmax, __shfl_xor(lmax, 32));  // partner lane has other half of keys

        // ---- online softmax (m, l per q-row; identical in partner lanes)
        const float mnew = fmaxf(m, lmax);
        const float corr = __builtin_amdgcn_exp2f((m - mnew) * L2E);
        l *= corr;
        #pragma unroll
        for (int r = 0; r < 8; ++r) acc[r] *= corr;   // only rows d<16 matter
        const float negml = -mnew * L2E;
        float lsum = 0.f;
        #pragma unroll
        for (int kt = 0; kt < 4; ++kt) {
            #pragma unroll
            for (int r = 0; r < 16; ++r) {
                float pe = __builtin_amdgcn_exp2f(fmaf(p[kt][r], L2E, negml));
                p[kt][r] = pe;
                lsum += pe;
            }
        }
        lsum += __shfl_xor(lsum, 32);
        l += lsum;
        m = mnew;

        // ---- PV: 8 MFMAs of 16 keys each; P^T regs feed B-frag directly
        #pragma unroll
        for (int j = 0; j < 8; ++j) {
            union { bf16x8 v; short s[8]; } pf;
            #pragma unroll
            for (int e = 0; e < 8; ++e) pf.s[e] = f2bf(p[j >> 1][(j & 1)*8 + e]);
            Frag vf;
            vf.h2[0] = *(const short4v*)(vrow + k0 + j*16 + 4*hi);
            vf.h2[1] = *(const short4v*)(vrow + k0 + j*16 + 8 + 4*hi);
            acc = __builtin_amdgcn_mfma_f32_32x32x16_bf16(vf.v, pf.v, acc, 0, 0, 0);
        }
    }

    // ---- epilogue: lane owns q=qrow, d = {4hi..4hi+3, 8+4hi..8+4hi+3}
    const float invl = 1.0f / l;
    float* cbase = ctx_out + ((size_t)b * S_LEN + qrow) * DP + h * DK;
    float4 o1 = { acc[0]*invl, acc[1]*invl, acc[2]*invl, acc[3]*invl };
    float4 o2 = { acc[4]*invl, acc[5]*invl, acc[6]*invl, acc[7]*invl };
    *(float4*)(cbase + 4*hi) = o1;
    *(float4*)(cbase + 8 + 4*hi) = o2;
}

// ---------------- Kernel 3: FC (ctx @ Wfc) + LayerNorm ----------------
__global__ __launch_bounds__(256) void fc_ln(
    const float* __restrict__ ctx, const float* __restrict__ Wfc,
    const float* __restrict__ gamma, const float* __restrict__ beta,
    float* __restrict__ out)
{
    __shared__ float cs[4][DP];
    __shared__ float ys[4][256];
    __shared__ float red[8];
    const int t = threadIdx.x;
    const int row0 = blockIdx.x * 4;

    {
        int idx = t * 2;
        int r = idx >> 7, k = idx & 127;
        *(float2*)&cs[r][k] = *(const float2*)(ctx + (size_t)(row0 + r) * DP + k);
    }
    __syncthreads();

    float acc[4] = {0,0,0,0};
    for (int k = 0; k < DP; k += 4) {
        const float w0 = Wfc[(k+0)*DM + t];
        const float w1 = Wfc[(k+1)*DM + t];
        const float w2 = Wfc[(k+2)*DM + t];
        const float w3 = Wfc[(k+3)*DM + t];
        #pragma unroll
        for (int r = 0; r < 4; ++r) {
            float4 x = *(const float4*)&cs[r][k];
            acc[r] = fmaf(x.x, w0, fmaf(x.y, w1, fmaf(x.z, w2, fmaf(x.w, w3, acc[r]))));
        }
    }

    #pragma unroll
    for (int r = 0; r < 4; ++r) ys[r][t] = acc[r];
    __syncthreads();

    const int w = t >> 6, lj = t & 63;
    {
        float a0 = ys[w][lj], a1 = ys[w][lj+64], a2 = ys[w][lj+128], a3 = ys[w][lj+192];
        float s1 = a0 + a1 + a2 + a3;
        float s2 = a0*a0 + a1*a1 + a2*a2 + a3*a3;
        #pragma unroll
        for (int off = 32; off; off >>= 1) {
            s1 += __shfl_xor(s1, off);
            s2 += __shfl_xor(s2, off);
        }
        if (lj == 0) {
            float mu = s1 * (1.0f/256.0f);
            float var = s2 * (1.0f/256.0f) - mu*mu;
            red[w*2]     = mu;
            red[w*2 + 1] = rsqrtf(var + 1e-5f);
        }
    }
    __syncthreads();

    const float g = gamma[t], be = beta[t];
    #pragma unroll
    for (int r = 0; r < 4; ++r) {
        float y = (acc[r] - red[r*2]) * red[r*2 + 1];
        out[(size_t)(row0 + r) * DM + t] = fmaf(y, g, be);
    }
}

extern "C" void kernel_launch(void* const* d_in, const int* in_sizes, int n_in,
                              void* d_out, int out_size, void* d_ws, size_t ws_size,
                              hipStream_t stream)
{
    const float* Xq = (const float*)d_in[0];
    const float* Xk = (const float*)d_in[1];
    const float* Xv = (const float*)d_in[2];
    const void* mask_raw = d_in[3];
    const float* Wq  = (const float*)d_in[4];
    const float* Wk  = (const float*)d_in[5];
    const float* Wv  = (const float*)d_in[6];
    const float* Wfc = (const float*)d_in[7];
    const float* gamma = (const float*)d_in[8];
    const float* beta  = (const float*)d_in[9];
    float* out = (float*)d_out;

    const size_t headsz = (size_t)BATCH * NH * S_LEN * DK;      // 1,048,576 elems
    const size_t maskelems = (size_t)BATCH * S_LEN * S_LEN;     // 16.8M

    short* Qb = (short*)d_ws;            // 2MB bf16
    short* Kb = Qb + headsz;             // 2MB
    short* Vb = Kb + headsz;             // 2MB (transposed [bh][16][S])
    float* ctx = (float*)(Vb + headsz);  // 4MB f32 [B,S,128]
    unsigned long long* mpacked = (unsigned long long*)(ctx + (size_t)BATCH * S_LEN * DP);
    int* flag = (int*)(mpacked + maskelems / 64);

    hipMemsetAsync(flag, 0, sizeof(int), stream);
    detect_mask_dtype<<<dim3(1024), dim3(256), 0, stream>>>((const unsigned int*)mask_raw, flag);
    pack_mask<<<dim3(maskelems / 256), dim3(256), 0, stream>>>(mask_raw, mpacked, flag);

    proj_qkv<<<dim3(BATCH * S_LEN / 8), dim3(256), 0, stream>>>(Xq, Xk, Xv, Wq, Wk, Wv, Qb, Kb, Vb);
    attn_mfma<<<dim3(S_LEN / 128, BATCH * NH), dim3(256), 0, stream>>>(Qb, Kb, Vb, mpacked, ctx);
    fc_ln<<<dim3(BATCH * S_LEN / 4), dim3(256), 0, stream>>>(ctx, Wfc, gamma, beta, out);
}